// Round 1
// 120.961 us; speedup vs baseline: 1.1234x; 1.1234x over previous
//
#include <hip/hip_runtime.h>

// Chamfer NN, SINGLE-PASS: each (query-block, db-chunk) block computes every
// pairwise distance ONCE and updates BOTH directions:
//   - s2t (min over db points, per query) in registers, as before
//   - t2s (min over queries, per db point) via skewed LDS ds_min_i32, then
//     a per-chunk global atomicMin merge.
// This halves the pair count vs the previous 2-direction kernel (8 -> 5
// lane-ops per unique pair). All math is SCALAR fp32: v_pk_fma_f32 is a
// 2-pass op on the SIMD-32 (no cycle win on fp32) and the packed form cost
// ~25% extra in t-splat movs (R11 post-mortem: VALUBusy 66.6us vs 54.7us
// packed-math floor).
// LDS t2s trick: distances are >=0 on this data (verified: previous kernel
// clamped at 0 with absmax 0.0), so float bits order correctly as ints;
// any negative-eps candidates clamp to 0 at the global merge either way.
// Skew j=(tid+s)&127 -> 64 distinct LDS addresses per wave for both the
// ds_read_b128 (stride 16B, canonical) and ds_min_i32 (stride 4B).

constexpr int BATCH  = 8;
constexpr int NPTS   = 8192;           // N == M
constexpr int TCHUNK = 128;            // db points staged in LDS per block
constexpr int NSPLIT = NPTS / TCHUNK;  // 64 db chunks (grid.z)
constexpr int BLOCK  = 256;
constexpr int IPT    = 16;             // queries per thread
constexpr int QPB    = BLOCK * IPT;    // 4096 queries per block
constexpr int QBLKS  = NPTS / QPB;     // 2 query blocks

static __device__ __forceinline__ float fmin3(float a, float b, float c) {
    // nested fminf -> v_min3_f32 (T17-style fusion)
    return fminf(fminf(a, b), c);
}

__global__ __launch_bounds__(BLOCK) void chamfer_nn_kernel(
    const float* __restrict__ src, const float* __restrict__ tgt,
    unsigned int* __restrict__ mins)   // [2][BATCH][NPTS] float-as-uint
{
    __shared__ float4 sh[TCHUNK];   // (x, y, z, 0.5*|t|^2)
    __shared__ int    sht[TCHUNK];  // per-db-point t2s partial min (float bits)

    const int tid   = threadIdx.x;
    const int xblk  = blockIdx.x;
    const int b     = blockIdx.y;
    const int chunk = blockIdx.z;

    // --- stage db chunk (tgt) into LDS; init t2s partials ---
    if (tid < TCHUNK) {
        const float* dbase = tgt + ((size_t)b * NPTS + (size_t)chunk * TCHUNK) * 3;
        float x = dbase[3 * tid + 0];
        float y = dbase[3 * tid + 1];
        float z = dbase[3 * tid + 2];
        sh[tid]  = make_float4(x, y, z, 0.5f * fmaf(x, x, fmaf(y, y, z * z)));
        sht[tid] = 0x7f7f7f7f;  // ~3.39e38 as float, large positive as int
    }

    // --- load my IPT queries (negated coords) + |q|^2 ---
    float qnx[IPT], qny[IPT], qnz[IPT], qs[IPT], mn[IPT];
    const int q0 = xblk * QPB + tid;
    const float* pbase = src + (size_t)b * NPTS * 3;
#pragma unroll
    for (int k = 0; k < IPT; k++) {
        const float* p = pbase + (size_t)(q0 + k * BLOCK) * 3;
        float x = p[0], y = p[1], z = p[2];
        qnx[k] = -x; qny[k] = -y; qnz[k] = -z;
        qs[k]  = fmaf(x, x, fmaf(y, y, z * z));
        mn[k]  = 3.4e38f;
    }
    __syncthreads();

    // --- main loop: 2 db points x 16 queries per iter ---
    // per iter: 2 ds_read_b128 + 2 ds_min_i32 (DS) and
    //           32 chain-fma + 32 d-fma + 16 min3 (VALU) -> 5 ops/pair
#pragma unroll 2
    for (int s = 0; s < TCHUNK; s += 2) {
        const int j0 = (tid + s) & (TCHUNK - 1);
        const int j1 = (tid + s + 1) & (TCHUNK - 1);
        const float4 t0 = sh[j0];
        const float4 t1 = sh[j1];
        float r0 = 3.4e38f, r1 = 3.4e38f;
#pragma unroll
        for (int k = 0; k < IPT; k += 2) {
            // d = |q|^2 + 2*(0.5|t|^2 - q.t); fma(2,v,qs) is monotonic in v,
            // so min-then-transform == transform-then-min (s2t stays
            // bit-identical to the verified 2-pass kernel).
            float v00 = fmaf(qnx[k],   t0.x, fmaf(qny[k],   t0.y, fmaf(qnz[k],   t0.z, t0.w)));
            float v01 = fmaf(qnx[k],   t1.x, fmaf(qny[k],   t1.y, fmaf(qnz[k],   t1.z, t1.w)));
            float v10 = fmaf(qnx[k+1], t0.x, fmaf(qny[k+1], t0.y, fmaf(qnz[k+1], t0.z, t0.w)));
            float v11 = fmaf(qnx[k+1], t1.x, fmaf(qny[k+1], t1.y, fmaf(qnz[k+1], t1.z, t1.w)));
            float d00 = fmaf(2.0f, v00, qs[k]);
            float d01 = fmaf(2.0f, v01, qs[k]);
            float d10 = fmaf(2.0f, v10, qs[k+1]);
            float d11 = fmaf(2.0f, v11, qs[k+1]);
            mn[k]   = fmin3(mn[k],   d00, d01);   // s2t: min over db points
            mn[k+1] = fmin3(mn[k+1], d10, d11);
            r0 = fmin3(r0, d00, d10);             // t2s: min over my 16 queries
            r1 = fmin3(r1, d01, d11);
        }
        atomicMin(&sht[j0], __float_as_int(r0));  // ds_min_i32, no-return
        atomicMin(&sht[j1], __float_as_int(r1));
    }

    // --- s2t merge: per-query min -> global (64 chunk-blocks contend) ---
    unsigned int* m0 = mins + (size_t)b * NPTS;
#pragma unroll
    for (int k = 0; k < IPT; k++) {
        float d = fmaxf(mn[k], 0.0f);
        atomicMin(&m0[q0 + k * BLOCK], __float_as_uint(d));
    }

    // --- t2s merge: per-db-point partial -> global (QBLKS=2 blocks contend) ---
    __syncthreads();
    if (tid < TCHUNK) {
        unsigned int* m1 = mins + ((size_t)BATCH + b) * NPTS + (size_t)chunk * TCHUNK;
        float d = fmaxf(__int_as_float(sht[tid]), 0.0f);
        atomicMin(&m1[tid], __float_as_uint(d));
    }
}

// One block per batch (1024 threads): sum final mins for both directions.
// 512 KB total, L2-resident. Stream ordering guarantees visibility.
__global__ __launch_bounds__(1024) void chamfer_out_kernel(
    const unsigned int* __restrict__ mins, float* __restrict__ out)
{
    const int b = blockIdx.x;
    float acc = 0.0f;
    for (int dir = 0; dir < 2; dir++) {
        const unsigned int* p = mins + ((size_t)dir * BATCH + b) * NPTS;
        for (int q = threadIdx.x; q < NPTS; q += 1024)
            acc += __uint_as_float(p[q]);
    }
    // wave (64-lane) shuffle reduction, then cross-wave via LDS
    for (int off = 32; off > 0; off >>= 1) acc += __shfl_down(acc, off, 64);
    __shared__ float wsum[16];
    const int lane = threadIdx.x & 63;
    const int wid  = threadIdx.x >> 6;
    if (lane == 0) wsum[wid] = acc;
    __syncthreads();
    if (threadIdx.x < 64) {
        float s = (threadIdx.x < 16) ? wsum[threadIdx.x] : 0.0f;
        for (int off = 8; off > 0; off >>= 1) s += __shfl_down(s, off, 64);
        if (threadIdx.x == 0) out[b] = s * (1.0f / (float)NPTS);
    }
}

extern "C" void kernel_launch(void* const* d_in, const int* in_sizes, int n_in,
                              void* d_out, int out_size, void* d_ws, size_t ws_size,
                              hipStream_t stream) {
    const float* src = (const float*)d_in[0];  // [B, N, 3]
    const float* tgt = (const float*)d_in[1];  // [B, M, 3]
    float* out = (float*)d_out;                // [B]

    unsigned int* mins = (unsigned int*)d_ws;  // [2][B][NPTS] = 512 KB
    const size_t min_bytes = (size_t)2 * BATCH * NPTS * sizeof(unsigned int);

    // Init mins to a huge positive float (0x7f7f7f7f ~= 3.39e38). Workspace is
    // re-poisoned before every timed call, so this must run every launch.
    hipMemsetAsync(d_ws, 0x7f, min_bytes, stream);

    dim3 grid(QBLKS, BATCH, NSPLIT);  // 2 x 8 x 64 = 1024 blocks
    chamfer_nn_kernel<<<grid, BLOCK, 0, stream>>>(src, tgt, mins);

    chamfer_out_kernel<<<BATCH, 1024, 0, stream>>>(mins, out);
}